// Round 1
// baseline (4636.313 us; speedup 1.0000x reference)
//
#include <hip/hip_runtime.h>
#include <cstdint>
#include <cstddef>

// Problem constants: B=4, T=2048, C=1024, H=16, d=64
#define T_SEQ 2048
#define CEMB  1024
#define NHEAD 16
#define DHEAD 64

// ---------------------------------------------------------------------------
// GEMM with bias: C[M][N] = A[M][K] @ B[K][N] + bias[N]
// 128x128 tile, BK=16, 256 threads, 8x8 micro-tile per thread (split 4+4).
// fp32 vector FMA (no fp32 MFMA on CDNA4).
// ---------------------------------------------------------------------------
__global__ __launch_bounds__(256) void gemm_bias_kernel(
    const float* __restrict__ A, const float* __restrict__ B,
    const float* __restrict__ bias, float* __restrict__ C,
    int M, int N, int K)
{
    __shared__ float As[16][128];   // [k][m]
    __shared__ float Bs[16][128];   // [k][n]

    const int tid = threadIdx.x;
    const int tx  = tid & 15;   // 0..15 -> output cols
    const int ty  = tid >> 4;   // 0..15 -> output rows

    const int row0 = blockIdx.y * 128;
    const int col0 = blockIdx.x * 128;

    float acc[2][2][4][4];
    #pragma unroll
    for (int a = 0; a < 2; ++a)
        #pragma unroll
        for (int b = 0; b < 2; ++b)
            #pragma unroll
            for (int i = 0; i < 4; ++i)
                #pragma unroll
                for (int j = 0; j < 4; ++j)
                    acc[a][b][i][j] = 0.f;

    const float* Ab = A + (size_t)row0 * K;
    const float* Bb = B + col0;

    for (int kt = 0; kt < K; kt += 16) {
        __syncthreads();
        // Load A tile (transpose to [k][m]): 512 float4 slots
        #pragma unroll
        for (int i = 0; i < 2; ++i) {
            int s  = tid + i * 256;
            int mm = s >> 2;           // 0..127
            int kq = s & 3;            // float4 index along k
            float4 f = *(const float4*)(Ab + (size_t)mm * K + kt + kq * 4);
            As[kq * 4 + 0][mm] = f.x;
            As[kq * 4 + 1][mm] = f.y;
            As[kq * 4 + 2][mm] = f.z;
            As[kq * 4 + 3][mm] = f.w;
        }
        // Load B tile ([k][n], direct): 512 float4 slots
        #pragma unroll
        for (int i = 0; i < 2; ++i) {
            int s  = tid + i * 256;
            int kk = s >> 5;           // 0..15
            int nq = s & 31;           // 0..31
            float4 f = *(const float4*)(Bb + (size_t)(kt + kk) * N + nq * 4);
            *(float4*)&Bs[kk][nq * 4] = f;
        }
        __syncthreads();

        #pragma unroll
        for (int k = 0; k < 16; ++k) {
            float4 a0 = *(const float4*)&As[k][ty * 4];
            float4 a1 = *(const float4*)&As[k][64 + ty * 4];
            float4 b0 = *(const float4*)&Bs[k][tx * 4];
            float4 b1 = *(const float4*)&Bs[k][64 + tx * 4];
            float av[2][4] = {{a0.x, a0.y, a0.z, a0.w}, {a1.x, a1.y, a1.z, a1.w}};
            float bv[2][4] = {{b0.x, b0.y, b0.z, b0.w}, {b1.x, b1.y, b1.z, b1.w}};
            #pragma unroll
            for (int ri = 0; ri < 2; ++ri)
                #pragma unroll
                for (int ci = 0; ci < 2; ++ci)
                    #pragma unroll
                    for (int i = 0; i < 4; ++i)
                        #pragma unroll
                        for (int j = 0; j < 4; ++j)
                            acc[ri][ci][i][j] += av[ri][i] * bv[ci][j];
        }
    }

    // Epilogue: add bias, store float4
    #pragma unroll
    for (int ri = 0; ri < 2; ++ri) {
        #pragma unroll
        for (int i = 0; i < 4; ++i) {
            int row = row0 + ri * 64 + ty * 4 + i;
            #pragma unroll
            for (int ci = 0; ci < 2; ++ci) {
                int col = col0 + ci * 64 + tx * 4;
                float4 bv = *(const float4*)(bias + col);
                float4 r;
                r.x = acc[ri][ci][i][0] + bv.x;
                r.y = acc[ri][ci][i][1] + bv.y;
                r.z = acc[ri][ci][i][2] + bv.z;
                r.w = acc[ri][ci][i][3] + bv.w;
                *(float4*)(C + (size_t)row * N + col) = r;
            }
        }
    }
}

// ---------------------------------------------------------------------------
// Causal flash attention, one thread per q row, fp32.
// qkv layout: [B, T, 3C] ; head h: q at h*64, k at C + h*64, v at 2C + h*64.
// Logits = (q . k) * sqrt(C) = dot(32*q, k)   (faithful reference quirk).
// KV streamed in 32-row LDS tiles with online softmax.
// ---------------------------------------------------------------------------
__global__ __launch_bounds__(256) void attn_kernel(
    const float* __restrict__ qkv, float* __restrict__ ctx)
{
    __shared__ float Ks[32][64];
    __shared__ float Vs[32][64];

    const int tid = threadIdx.x;
    const int b   = blockIdx.z;
    const int h   = blockIdx.y;
    const int r0  = blockIdx.x * 256;
    const int r   = r0 + tid;
    const int iq  = r;

    const float* qrow = qkv + (size_t)(b * T_SEQ + r) * (3 * CEMB) + h * DHEAD;
    float q[DHEAD];
    #pragma unroll
    for (int c = 0; c < DHEAD; c += 4) {
        float4 f = *(const float4*)(qrow + c);
        q[c]     = f.x * 32.0f;
        q[c + 1] = f.y * 32.0f;
        q[c + 2] = f.z * 32.0f;
        q[c + 3] = f.w * 32.0f;
    }

    float o[DHEAD];
    #pragma unroll
    for (int c = 0; c < DHEAD; ++c) o[c] = 0.f;
    float m = -3.0e38f;
    float l = 0.f;

    const float* kbase = qkv + (size_t)(b * T_SEQ) * (3 * CEMB) + CEMB + h * DHEAD;
    const float* vbase = kbase + CEMB;

    const int wmax  = iq | 63;          // max valid j for this wave (rows contiguous)
    const int ntile = (r0 >> 5) + 8;    // covers j <= r0 + 255

    for (int t = 0; t < ntile; ++t) {
        const int jt = t * 32;
        __syncthreads();
        // Cooperative load of K and V tiles: 512 float4 each
        #pragma unroll
        for (int i = 0; i < 2; ++i) {
            int s  = tid * 2 + i;       // 0..511
            int j  = s >> 4;            // 0..31
            int cq = (s & 15) * 4;      // 0..60
            *(float4*)&Ks[j][cq] = *(const float4*)(kbase + (size_t)(jt + j) * (3 * CEMB) + cq);
            *(float4*)&Vs[j][cq] = *(const float4*)(vbase + (size_t)(jt + j) * (3 * CEMB) + cq);
        }
        __syncthreads();

        if (jt <= wmax) {   // wave-uniform causal early-out
            float sv[32];
            float tmax = -3.0e38f;
            #pragma unroll
            for (int j = 0; j < 32; ++j) {
                float d0 = 0.f, d1 = 0.f, d2 = 0.f, d3 = 0.f;
                #pragma unroll
                for (int c = 0; c < DHEAD; c += 4) {
                    float4 kk = *(const float4*)&Ks[j][c];
                    d0 += q[c]     * kk.x;
                    d1 += q[c + 1] * kk.y;
                    d2 += q[c + 2] * kk.z;
                    d3 += q[c + 3] * kk.w;
                }
                float d = (d0 + d1) + (d2 + d3);
                d = (jt + j <= iq) ? d : -3.0e38f;
                sv[j] = d;
                tmax = fmaxf(tmax, d);
            }
            float mnew  = fmaxf(m, tmax);
            float alpha = __expf(m - mnew);   // 0 on first tile, 1 when no new max
            l *= alpha;
            #pragma unroll
            for (int c = 0; c < DHEAD; ++c) o[c] *= alpha;
            m = mnew;

            #pragma unroll
            for (int j = 0; j < 32; ++j) {
                float p = __expf(sv[j] - m);  // masked -> underflows to exactly 0
                l += p;
                #pragma unroll
                for (int c = 0; c < DHEAD; c += 4) {
                    float4 vv = *(const float4*)&Vs[j][c];
                    o[c]     += p * vv.x;
                    o[c + 1] += p * vv.y;
                    o[c + 2] += p * vv.z;
                    o[c + 3] += p * vv.w;
                }
            }
        }
    }

    const float inv = 1.0f / l;
    float* orow = ctx + (size_t)(b * T_SEQ + r) * CEMB + h * DHEAD;
    #pragma unroll
    for (int c = 0; c < DHEAD; c += 4) {
        float4 f;
        f.x = o[c] * inv;
        f.y = o[c + 1] * inv;
        f.z = o[c + 2] * inv;
        f.w = o[c + 3] * inv;
        *(float4*)(orow + c) = f;
    }
}

// ---------------------------------------------------------------------------
extern "C" void kernel_launch(void* const* d_in, const int* in_sizes, int n_in,
                              void* d_out, int out_size, void* d_ws, size_t ws_size,
                              hipStream_t stream)
{
    const float* x    = (const float*)d_in[0];   // [4,2048,1024]
    const float* Wqkv = (const float*)d_in[1];   // [1024,3072]
    const float* bqkv = (const float*)d_in[2];   // [3072]
    const float* Wo   = (const float*)d_in[3];   // [1024,1024]
    const float* bo   = (const float*)d_in[4];   // [1024]
    // d_in[5] = decoder (==1, causal hardcoded)
    float* out = (float*)d_out;                  // [4,2048,1024]

    float* qkv = (float*)d_ws;                       // 8192*3072 floats (96 MiB)
    float* ctx = qkv + (size_t)8192 * 3072;          // 8192*1024 floats (32 MiB)

    const int M = 4 * T_SEQ;  // 8192

    // 1) qkv = x @ Wqkv + bqkv
    gemm_bias_kernel<<<dim3(3 * CEMB / 128, M / 128), 256, 0, stream>>>(
        x, Wqkv, bqkv, qkv, M, 3 * CEMB, CEMB);

    // 2) causal attention -> ctx [B,T,C]
    attn_kernel<<<dim3(T_SEQ / 256, NHEAD, 4), 256, 0, stream>>>(qkv, ctx);

    // 3) out = ctx @ Wo + bo
    gemm_bias_kernel<<<dim3(CEMB / 128, M / 128), 256, 0, stream>>>(
        ctx, Wo, bo, out, M, CEMB, CEMB);
}